// Round 5
// baseline (162.555 us; speedup 1.0000x reference)
//
#include <hip/hip_runtime.h>

// Problem constants (match reference file)
#define B_DIM 512
#define S_DIM 1024
#define NTOK (B_DIM * S_DIM)          // 524288 tokens
#define CHAR_LEN 32
#define MAX_CANDS 4000
#define N_PRIV 8
#define CTX_RATE 0.15f

typedef int vint4 __attribute__((ext_vector_type(4)));  // clang-native 16B vector

// Output layout (concatenated flat, int32):
//   [0*NTOK)   obf_word
//   [1*NTOK)   inp_word (copy)
//   [2*NTOK)   obf_char (NTOK*32)
//   [34*NTOK)  inp_pos (copy)
//   [35*NTOK)  obf_mask (0/1)
//   [36*NTOK)  pri_mask (0/1)
//   [37*NTOK)  cpy_mask (0/1)

__global__ __launch_bounds__(256) void alltag_kernel(
    const int* __restrict__ inp_word,
    const int* __restrict__ inp_pos,
    const int* __restrict__ inp_mask,
    const float* __restrict__ ctx_rand,
    const float* __restrict__ pri_rand,
    const float* __restrict__ cand_u,
    const vint4* __restrict__ lut4,      // [VOCAB][8] vint4
    const int* __restrict__ tgt_table,   // [N_POS][MAX_CANDS]
    const int* __restrict__ counts,      // [N_POS]
    int* __restrict__ out)
{
    const int token = blockIdx.x * blockDim.x + threadIdx.x;   // [0, NTOK)
    const int lane  = threadIdx.x & 63;
    const int wbase = token - lane;      // first token of this wave's 64

    // ---- Phase A: 1 lane = 1 token (coalesced scalars), no LDS, no barrier
    int   pos  = __builtin_nontemporal_load(&inp_pos[token]);
    int   word = __builtin_nontemporal_load(&inp_word[token]);
    float cr   = __builtin_nontemporal_load(&ctx_rand[token]);
    float pr   = __builtin_nontemporal_load(&pri_rand[token]);
    float cu   = __builtin_nontemporal_load(&cand_u[token]);
    int   msk  = __builtin_nontemporal_load(&inp_mask[token]);

    bool pri_mask = (pos < N_PRIV);              // priv_pos = arange < N_PRIV
    bool obf = pri_mask ? (pr < 1.0f) : (cr < CTX_RATE);

    int cnt = counts[pos];                       // 160B, L1-resident
    int idx = (int)(cu * (float)cnt);            // JAX trunc semantics
    idx = min(idx, cnt - 1);
    int cdt = tgt_table[pos * MAX_CANDS + idx];  // 640KB, L2-resident
    int ow  = obf ? cdt : word;                  // obf_word, stays in-register

    __builtin_nontemporal_store(ow, &out[token]);
    __builtin_nontemporal_store(word, &out[NTOK + token]);
    __builtin_nontemporal_store(pos, &out[(size_t)NTOK * 34 + token]);
    __builtin_nontemporal_store(obf ? 1 : 0, &out[(size_t)NTOK * 35 + token]);
    __builtin_nontemporal_store(pri_mask ? 1 : 0, &out[(size_t)NTOK * 36 + token]);
    bool cpy = (msk != 0) && (word == ow);
    __builtin_nontemporal_store(cpy ? 1 : 0, &out[(size_t)NTOK * 37 + token]);

    // ---- Phase B: 8 lanes/token via in-wave shuffle broadcast -------------
    const int sub = lane & 7;            // which 16B chunk of the 128B row
    const int grp = lane >> 3;           // [0,8): token slot within octet
    vint4* out_char4 = (vint4*)(out + (size_t)NTOK * 2);

#pragma unroll
    for (int i = 0; i < 8; ++i) {
        int w = __shfl(ow, 8 * i + grp, 64);      // broadcast token's obf_word
        int t = wbase + 8 * i + grp;              // token handled this iter
        vint4 v = lut4[w * 8 + sub];              // random 16B gather (cached)
        __builtin_nontemporal_store(v, &out_char4[(size_t)t * 8 + sub]);
    }
}

extern "C" void kernel_launch(void* const* d_in, const int* in_sizes, int n_in,
                              void* d_out, int out_size, void* d_ws, size_t ws_size,
                              hipStream_t stream) {
    const int*   inp_word  = (const int*)  d_in[0];
    const int*   inp_pos   = (const int*)  d_in[2];
    const int*   inp_mask  = (const int*)  d_in[3];
    const float* ctx_rand  = (const float*)d_in[4];
    const float* pri_rand  = (const float*)d_in[5];
    const float* cand_u    = (const float*)d_in[6];
    const vint4* lut4      = (const vint4*)d_in[7];
    const int*   tgt_table = (const int*)  d_in[8];
    const int*   counts    = (const int*)  d_in[9];
    int* out = (int*)d_out;

    const int block = 256;
    const int grid  = NTOK / block;          // 2048 blocks = 8192 waves (full)
    alltag_kernel<<<grid, block, 0, stream>>>(inp_word, inp_pos, inp_mask,
                                              ctx_rand, pri_rand, cand_u,
                                              lut4, tgt_table, counts, out);
}

// Round 6
// 161.500 us; speedup vs baseline: 1.0065x; 1.0065x over previous
//
#include <hip/hip_runtime.h>

// Problem constants (match reference file)
#define B_DIM 512
#define S_DIM 1024
#define NTOK (B_DIM * S_DIM)          // 524288 tokens
#define CHAR_LEN 32
#define MAX_CANDS 4000
#define N_PRIV 8
#define CTX_RATE 0.15f

typedef int vint4 __attribute__((ext_vector_type(4)));  // clang-native 16B vector

// Output layout (concatenated flat, int32):
//   [0*NTOK)   obf_word
//   [1*NTOK)   inp_word (copy)
//   [2*NTOK)   obf_char (NTOK*32)
//   [34*NTOK)  inp_pos (copy)
//   [35*NTOK)  obf_mask (0/1)
//   [36*NTOK)  pri_mask (0/1)
//   [37*NTOK)  cpy_mask (0/1)

__global__ __launch_bounds__(256) void alltag_kernel(
    const int* __restrict__ inp_word,
    const int* __restrict__ inp_pos,
    const int* __restrict__ inp_mask,
    const float* __restrict__ ctx_rand,
    const float* __restrict__ pri_rand,
    const float* __restrict__ cand_u,
    const vint4* __restrict__ lut4,      // [VOCAB][8] vint4
    const int* __restrict__ tgt_table,   // [N_POS][MAX_CANDS]
    const int* __restrict__ counts,      // [N_POS]
    int* __restrict__ out)
{
    // Each wave owns a private 128-token LDS slice -> no __syncthreads needed
    // (a wave's DS ops execute in order; no cross-wave LDS sharing).
    __shared__ int s_ow[512];

    const int tid       = threadIdx.x;
    const int lane      = tid & 63;
    const int wave      = tid >> 6;                       // [0,4)
    const int wave_base = blockIdx.x * 512 + wave * 128;  // this wave's tokens

    // ---- Phase A: 2 tokens per lane (independent chains, coalesced) -------
#pragma unroll
    for (int k = 0; k < 2; ++k) {
        const int token = wave_base + k * 64 + lane;
        int   pos  = __builtin_nontemporal_load(&inp_pos[token]);
        int   word = __builtin_nontemporal_load(&inp_word[token]);
        float cr   = __builtin_nontemporal_load(&ctx_rand[token]);
        float pr   = __builtin_nontemporal_load(&pri_rand[token]);
        float cu   = __builtin_nontemporal_load(&cand_u[token]);
        int   msk  = __builtin_nontemporal_load(&inp_mask[token]);

        bool pri_mask = (pos < N_PRIV);              // priv_pos = arange < N_PRIV
        bool obf = pri_mask ? (pr < 1.0f) : (cr < CTX_RATE);

        int cnt = counts[pos];                       // 160B, L1-resident
        int idx = (int)(cu * (float)cnt);            // JAX trunc semantics
        idx = min(idx, cnt - 1);
        int cdt = tgt_table[pos * MAX_CANDS + idx];  // 640KB, L2-resident
        int ow  = obf ? cdt : word;

        s_ow[wave * 128 + k * 64 + lane] = ow;       // stride-1: free 2-way

        __builtin_nontemporal_store(ow, &out[token]);
        __builtin_nontemporal_store(word, &out[NTOK + token]);
        __builtin_nontemporal_store(pos, &out[(size_t)NTOK * 34 + token]);
        __builtin_nontemporal_store(obf ? 1 : 0, &out[(size_t)NTOK * 35 + token]);
        __builtin_nontemporal_store(pri_mask ? 1 : 0, &out[(size_t)NTOK * 36 + token]);
        bool cpy = (msk != 0) && (word == ow);
        __builtin_nontemporal_store(cpy ? 1 : 0, &out[(size_t)NTOK * 37 + token]);
    }

    // ---- Phase B: 16 independent lut gathers per thread (wave-local) ------
    const int sub = lane & 7;            // 16B chunk of the 128B row
    const int grp = lane >> 3;           // [0,8): token slot within octet
    vint4* out_char4 = (vint4*)(out + (size_t)NTOK * 2);

#pragma unroll
    for (int i = 0; i < 16; ++i) {
        int lt = 8 * i + grp;                         // [0,128) in wave slice
        int w  = s_ow[wave * 128 + lt];               // broadcast read (free)
        int t  = wave_base + lt;
        vint4 v = lut4[w * 8 + sub];                  // random 16B gather
        __builtin_nontemporal_store(v, &out_char4[(size_t)t * 8 + sub]);
    }
}

extern "C" void kernel_launch(void* const* d_in, const int* in_sizes, int n_in,
                              void* d_out, int out_size, void* d_ws, size_t ws_size,
                              hipStream_t stream) {
    const int*   inp_word  = (const int*)  d_in[0];
    const int*   inp_pos   = (const int*)  d_in[2];
    const int*   inp_mask  = (const int*)  d_in[3];
    const float* ctx_rand  = (const float*)d_in[4];
    const float* pri_rand  = (const float*)d_in[5];
    const float* cand_u    = (const float*)d_in[6];
    const vint4* lut4      = (const vint4*)d_in[7];
    const int*   tgt_table = (const int*)  d_in[8];
    const int*   counts    = (const int*)  d_in[9];
    int* out = (int*)d_out;

    const int block = 256;
    const int grid  = NTOK / 512;            // 1024 blocks, 512 tokens each
    alltag_kernel<<<grid, block, 0, stream>>>(inp_word, inp_pos, inp_mask,
                                              ctx_rand, pri_rand, cand_u,
                                              lut4, tgt_table, counts, out);
}